// Round 1
// baseline (325.580 us; speedup 1.0000x reference)
//
#include <hip/hip_runtime.h>

// Pure permutation kernel for KernelActivation (k=2).
// out[b, ((i*112+j)*224+w)*4 + p*2 + q] = x[b, 2i+p, 2j+q, w]
// Each thread produces one aligned float4 of the output (one (i,j,w) group),
// gathering 4 scalars from input. Across a wave, lanes have consecutive w,
// so each of the 4 loads is a contiguous coalesced 256B wave transaction.

constexpr int Wd = 224;
constexpr int Hd = 224;
constexpr int Cd = 64;
constexpr int HW = Hd * Wd;          // 50176
constexpr int HALF_H = Hd / 2;       // 112
constexpr int HALF_C = Cd / 2;       // 32

__global__ __launch_bounds__(256)
void permute_kernel(const float* __restrict__ x, float4* __restrict__ out, int n_groups) {
    int g = blockIdx.x * blockDim.x + threadIdx.x;
    if (g >= n_groups) return;

    int w = g % Wd;
    int t = g / Wd;
    int j = t % HALF_H;
    int u = t / HALF_H;
    int i = u % HALF_C;
    int b = u / HALF_C;

    const float* __restrict__ p = x + (((size_t)(b * Cd + 2 * i) * Hd + 2 * j) * Wd + w);
    float v00 = p[0];          // p=0,q=0 : c=2i,   h=2j
    float v01 = p[Wd];         // p=0,q=1 : c=2i,   h=2j+1
    float v10 = p[HW];         // p=1,q=0 : c=2i+1, h=2j
    float v11 = p[HW + Wd];    // p=1,q=1 : c=2i+1, h=2j+1

    out[g] = make_float4(v00, v01, v10, v11);
}

extern "C" void kernel_launch(void* const* d_in, const int* in_sizes, int n_in,
                              void* d_out, int out_size, void* d_ws, size_t ws_size,
                              hipStream_t stream) {
    const float* x = (const float*)d_in[0];
    float4* out = (float4*)d_out;

    // total output floats = 16*64*224*224 = 51,380,224 ; groups of 4
    int n_groups = out_size / 4;  // 12,845,056
    int block = 256;
    int grid = (n_groups + block - 1) / block;  // 50,176

    permute_kernel<<<grid, block, 0, stream>>>(x, out, n_groups);
}